// Round 8
// baseline (333.305 us; speedup 1.0000x reference)
//
#include <hip/hip_runtime.h>

#define BB 4
#define CC 64
#define HH 128
#define WW 128
#define NN 16
#define HW (HH*WW)

#if __has_builtin(__builtin_amdgcn_exp2f)
#define EXP2F(x) __builtin_amdgcn_exp2f(x)
#else
#define EXP2F(x) exp2f(x)
#endif

__device__ __forceinline__ float softplus_f(float x) {
    float e = __expf(-fabsf(x));
    return fmaxf(x, 0.0f) + __logf(1.0f + e);
}

// float2 helpers: written so SLP can form v_pk_fma_f32 / v_pk_mul_f32.
__device__ __forceinline__ float2 f2mul(float2 a, float2 b) {
    return make_float2(a.x * b.x, a.y * b.y);
}
__device__ __forceinline__ float2 f2fma(float2 a, float2 b, float2 c) {
    return make_float2(fmaf(a.x, b.x, c.x), fmaf(a.y, b.y, c.y));
}

// ===========================================================================
// Fused proj+scan, launched TWICE (512 blocks each; half is a kernel arg):
//   pass 0 (h): scan row (b,L=h), plain stores -> out[b,c,h,:] (covers all
//               cells; kernel boundary orders pass0 before pass1)
//   pass 1 (v): scan col (b,L=w), atomicAdd y -> out[b,c,h,w] directly
// R19: k_add + yv ELIMINATED. Evidence: residual (total - k_scan) was a
// constant ~70us across R0-R18 while k_scan varied 79-154us -> k_add (+gap)
// is >= the cost of k_scan itself, at 8x its 8us roofline. Removing it cuts
// 50MB of yv/out round-trip traffic and one dispatch; fp32 atomicAdd is
// commutative so result is bit-identical (store + one add per cell).
// Scan body byte-identical to R18 (verified 80.4us / absmax 0.125):
// exp2-folded A, pk float2 pairs, dlt delta phase, 2 barriers/chunk,
// bid>>... mapping now trivial (one half per launch -> uniform per kernel).
// ===========================================================================
__global__ __launch_bounds__(256) void k_scan(
    const float* __restrict__ x, const float* __restrict__ xpw,
    const float* __restrict__ A_log, const float* __restrict__ Dv,
    const float* __restrict__ dtw, const float* __restrict__ dtb,
    float* __restrict__ out, int half)
{
    __shared__ float xt[128 * 64];   // 32 KB  x line, (j,c) at j*64+((c+j)&63)
    __shared__ float bcs[128 * 32];  // 16 KB  B/C, group g at j*32+((g^(j&7))<<2)
    __shared__ float dtr[128 * 4];   //  2 KB  dt_raw per pixel
    __shared__ float dlt[8 * 64];    //  2 KB  delta chunk [jl][d]

    const int t = threadIdx.x;
    const int b = blockIdx.x >> 7;
    const int L = blockIdx.x & 127;

    // ---- stage x line into swizzled xt ----
    if (half == 0) {
#pragma unroll
        for (int k = 0; k < 8; ++k) {            // rows: float4 coalesced global
            int i = k * 256 + t;
            int c = i >> 5, jq = i & 31;
            float4 v = *(const float4*)&x[((size_t)(b * CC + c) * HH + L) * WW + jq * 4];
            int j0 = jq * 4;
            xt[(j0 + 0) * 64 + ((c + j0 + 0) & 63)] = v.x;
            xt[(j0 + 1) * 64 + ((c + j0 + 1) & 63)] = v.y;
            xt[(j0 + 2) * 64 + ((c + j0 + 2) & 63)] = v.z;
            xt[(j0 + 3) * 64 + ((c + j0 + 3) & 63)] = v.w;
        }
    } else {
#pragma unroll
        for (int p = 0; p < 32; ++p) {           // cols: L2/L3-served gather
            int c = t & 63, j = p * 4 + (t >> 6);
            xt[j * 64 + ((c + j) & 63)] =
                x[((size_t)(b * CC + c) * HH + j) * WW + L];
        }
    }
    __syncthreads();

    // ---- proj: wave pair covers (64 pix) x (18 of 36 cols); xpw uniform ----
    {
        const int wv = t >> 6, lane = t & 63;
        const int pg2 = __builtin_amdgcn_readfirstlane(wv & 1);
        const int pix = (wv >> 1) * 64 + lane;
        const int p0 = pg2 * 18;
        const int sw = pix & 7;
        float acc[18];
#pragma unroll
        for (int j = 0; j < 18; ++j) acc[j] = 0.f;
        for (int c4 = 0; c4 < 16; ++c4) {
            float xv0 = xt[pix * 64 + ((c4 * 4 + 0 + pix) & 63)];
            float xv1 = xt[pix * 64 + ((c4 * 4 + 1 + pix) & 63)];
            float xv2 = xt[pix * 64 + ((c4 * 4 + 2 + pix) & 63)];
            float xv3 = xt[pix * 64 + ((c4 * 4 + 3 + pix) & 63)];
#pragma unroll
            for (int j = 0; j < 18; ++j) {
                float4 wq = *(const float4*)&xpw[(p0 + j) * CC + c4 * 4];
                acc[j] = fmaf(wq.x, xv0, fmaf(wq.y, xv1,
                         fmaf(wq.z, xv2, fmaf(wq.w, xv3, acc[j]))));
            }
        }
        float* bp = &bcs[pix * 32];
        if (pg2 == 0) {
            *(float4*)&dtr[pix * 4] = make_float4(acc[0], acc[1], acc[2], acc[3]);
            // B groups 0..2 full; group 3 split (B12,B13 here)
            *(float4*)&bp[((0 ^ sw) << 2)] = make_float4(acc[4], acc[5], acc[6], acc[7]);
            *(float4*)&bp[((1 ^ sw) << 2)] = make_float4(acc[8], acc[9], acc[10], acc[11]);
            *(float4*)&bp[((2 ^ sw) << 2)] = make_float4(acc[12], acc[13], acc[14], acc[15]);
            bp[((3 ^ sw) << 2) + 0] = acc[16];
            bp[((3 ^ sw) << 2) + 1] = acc[17];
        } else {
            // B14,B15 finish group 3; C groups 4..7 full
            bp[((3 ^ sw) << 2) + 2] = acc[0];
            bp[((3 ^ sw) << 2) + 3] = acc[1];
            *(float4*)&bp[((4 ^ sw) << 2)] = make_float4(acc[2], acc[3], acc[4], acc[5]);
            *(float4*)&bp[((5 ^ sw) << 2)] = make_float4(acc[6], acc[7], acc[8], acc[9]);
            *(float4*)&bp[((6 ^ sw) << 2)] = make_float4(acc[10], acc[11], acc[12], acc[13]);
            *(float4*)&bp[((7 ^ sw) << 2)] = make_float4(acc[14], acc[15], acc[16], acc[17]);
        }
    }

    // ---- scan setup; A pre-scaled by log2e so dA = v_exp directly ----
    const int d = t >> 2, ng = t & 3, n0 = ng * 4;
    const float L2E = 1.44269504088896340736f;
    float A0 = -__expf(A_log[d * NN + n0 + 0]) * L2E;
    float A1 = -__expf(A_log[d * NN + n0 + 1]) * L2E;
    float A2 = -__expf(A_log[d * NN + n0 + 2]) * L2E;
    float A3 = -__expf(A_log[d * NN + n0 + 3]) * L2E;
    const float Dd = Dv[d];
    float2 h01 = make_float2(0.f, 0.f), h23 = make_float2(0.f, 0.f);
    // delta-phase identity: 64 d x (2 j per thread)
    const int dd = t & 63, jb = t >> 6;
    const float4 wt4 = *(const float4*)&dtw[dd * 4];
    const float bdd = dtb[dd];
    // h-pass: row pointer out[b,d,L,:].  v-pass: column base out[b,d,0,L].
    float* drow = out + ((size_t)(b * CC + d) * 128 + L) * 128;
    float* dcol = out + ((size_t)(b * CC + d) * 128) * 128 + L;

    for (int ch = 0; ch < 16; ++ch) {
        __syncthreads();                         // prev chunk's dlt reads done / proj done
        // ---- delta precompute: once per (d,j), 2 j per thread (R0-exact) ----
#pragma unroll
        for (int k = 0; k < 2; ++k) {
            int jl = jb * 2 + k;
            float4 dr = *(const float4*)&dtr[(ch * 8 + jl) * 4];   // bcast
            float draw = fmaf(dr.x, wt4.x, fmaf(dr.y, wt4.y,
                         fmaf(dr.z, wt4.z, fmaf(dr.w, wt4.w, bdd))));
            dlt[jl * 64 + dd] = softplus_f(draw);
        }
        __syncthreads();
        // ---- 8 scan steps, no barriers; pk-paired fp32 ----
        float y0 = 0.f, y1 = 0.f;
#pragma unroll
        for (int jl = 0; jl < 8; ++jl) {
            const int j = ch * 8 + jl;
            float delta = dlt[jl * 64 + d];
            float u = xt[j * 64 + ((d + j) & 63)];
            const int s = j & 7;                 // == jl (compile-time)
            float4 Bv = *(const float4*)&bcs[j * 32 + ((ng ^ s) << 2)];
            float4 Cv = *(const float4*)&bcs[j * 32 + (((4 + ng) ^ s) << 2)];
            float du = delta * u;
            float2 e01 = make_float2(EXP2F(delta * A0), EXP2F(delta * A1));
            float2 e23 = make_float2(EXP2F(delta * A2), EXP2F(delta * A3));
            float2 du2 = make_float2(du, du);
            h01 = f2fma(e01, h01, f2mul(du2, make_float2(Bv.x, Bv.y)));
            h23 = f2fma(e23, h23, f2mul(du2, make_float2(Bv.z, Bv.w)));
            float2 yt = f2fma(h23, make_float2(Cv.z, Cv.w),
                              f2mul(h01, make_float2(Cv.x, Cv.y)));
            float y = yt.x + yt.y;
            y += __shfl_xor(y, 1);               // quad reduction
            y += __shfl_xor(y, 2);
            y = fmaf(u, Dd, y);
            if (ng == (jl >> 1)) { if (jl & 1) y1 = y; else y0 = y; }
        }
        if (half == 0) {
            *(float2*)&drow[ch * 8 + ng * 2] = make_float2(y0, y1);
        } else {
            // pixel index along the scan is h; column w = L is fixed.
            const int hp = ch * 8 + ng * 2;
            atomicAdd(&dcol[(size_t)hp * 128], y0);
            atomicAdd(&dcol[(size_t)(hp + 1) * 128], y1);
        }
    }
}

// ---------------------------------------------------------------------------
extern "C" void kernel_launch(void* const* d_in, const int* in_sizes, int n_in,
                              void* d_out, int out_size, void* d_ws, size_t ws_size,
                              hipStream_t stream) {
    const float* x     = (const float*)d_in[0];
    const float* A_log = (const float*)d_in[1];
    const float* Dv    = (const float*)d_in[2];
    const float* xpw   = (const float*)d_in[3];
    const float* dtw   = (const float*)d_in[4];
    const float* dtb   = (const float*)d_in[5];
    float* out = (float*)d_out;

    // pass 0: h-scan writes every out cell; pass 1: v-scan atomicAdds on top.
    // Kernel boundary on the stream orders the plain stores before the adds.
    k_scan<<<512, 256, 0, stream>>>(x, xpw, A_log, Dv, dtw, dtb, out, 0);
    k_scan<<<512, 256, 0, stream>>>(x, xpw, A_log, Dv, dtw, dtb, out, 1);
}

// Round 9
// 143.999 us; speedup vs baseline: 2.3146x; 2.3146x over previous
//
#include <hip/hip_runtime.h>

#define BB 4
#define CC 64
#define HH 128
#define WW 128
#define NN 16
#define HW (HH*WW)

#if __has_builtin(__builtin_amdgcn_exp2f)
#define EXP2F(x) __builtin_amdgcn_exp2f(x)
#else
#define EXP2F(x) exp2f(x)
#endif

__device__ __forceinline__ float softplus_f(float x) {
    float e = __expf(-fabsf(x));
    return fmaxf(x, 0.0f) + __logf(1.0f + e);
}

// float2 helpers: written so SLP can form v_pk_fma_f32 / v_pk_mul_f32.
__device__ __forceinline__ float2 f2mul(float2 a, float2 b) {
    return make_float2(a.x * b.x, a.y * b.y);
}
__device__ __forceinline__ float2 f2fma(float2 a, float2 b, float2 c) {
    return make_float2(fmaf(a.x, b.x, c.x), fmaf(a.y, b.y, c.y));
}

// Broadcast quad lane (base+SRC) to all 4 quad lanes. Pure-VALU DPP quad_perm.
// R12-verified numerically (absmax 0.125).
template<int SRC>
__device__ __forceinline__ float quad_bcast(float v) {
    return __int_as_float(__builtin_amdgcn_mov_dpp(
        __float_as_int(v), SRC * 0x55, 0xF, 0xF, true));
}

// ===========================================================================
// Fused proj+scan. grid 1024, block 256 = 64 d x 4 ng (4 SSM states/lane).
// Blocks [0,512): h-scan of row (b,L=h) -> out[b,c,h,:]
// Blocks [512,1024): v-scan of col (b,L=w) -> yv[b,c,w,:]  ([b][c][w][h])
// R20 = R18 skeleton (80 VGPR, 149.9us total — best known) with the dlt LDS
// round-trip replaced by quad-DPP delta broadcast: lane ng computes deltas
// for jl=ng,ng+4 (same VALU as the old dlt phase, same fma order -> bit-
// identical), mov_dpp broadcasts them. Removes 10 LDS ops + 2 barriers per
// chunk; scan is barrier-free. Model: VALU issue (~38us/SIMD) and LDS pipe
// (~35us/CU) are co-dominant (R16: +VALU costs 1:1; R18: -VALU gains 0) ->
// cut LDS. Structure identical to R16's proven-80-VGPR barrier-free loop
// (unroll-1 + sched_barrier fences); R12's 148-VGPR came from segmentation.
// R19 lesson: scattered atomics = 64B-line RMW per 4B (225us); also proved
// the ~62us residual is fixed harness overhead, not k_add.
// ===========================================================================
__global__ __launch_bounds__(256) void k_scan(
    const float* __restrict__ x, const float* __restrict__ xpw,
    const float* __restrict__ A_log, const float* __restrict__ Dv,
    const float* __restrict__ dtw, const float* __restrict__ dtb,
    float* __restrict__ out, float* __restrict__ yv)
{
    __shared__ float xt[128 * 64];   // 32 KB  x line, (j,c) at j*64+((c+j)&63)
    __shared__ float bcs[128 * 32];  // 16 KB  B/C, group g at j*32+((g^(j&7))<<2)
    __shared__ float dtr[128 * 4];   //  2 KB  dt_raw per pixel

    const int t = threadIdx.x;
    const int half = blockIdx.x >> 9;          // R0-proven balanced mapping
    const int r9 = blockIdx.x & 511;
    const int b = r9 >> 7;
    const int L = r9 & 127;

    // ---- stage x line into swizzled xt ----
    if (half == 0) {
#pragma unroll
        for (int k = 0; k < 8; ++k) {            // rows: float4 coalesced global
            int i = k * 256 + t;
            int c = i >> 5, jq = i & 31;
            float4 v = *(const float4*)&x[((size_t)(b * CC + c) * HH + L) * WW + jq * 4];
            int j0 = jq * 4;
            xt[(j0 + 0) * 64 + ((c + j0 + 0) & 63)] = v.x;
            xt[(j0 + 1) * 64 + ((c + j0 + 1) & 63)] = v.y;
            xt[(j0 + 2) * 64 + ((c + j0 + 2) & 63)] = v.z;
            xt[(j0 + 3) * 64 + ((c + j0 + 3) & 63)] = v.w;
        }
    } else {
#pragma unroll
        for (int p = 0; p < 32; ++p) {           // cols: L2/L3-served gather
            int c = t & 63, j = p * 4 + (t >> 6);
            xt[j * 64 + ((c + j) & 63)] =
                x[((size_t)(b * CC + c) * HH + j) * WW + L];
        }
    }
    __syncthreads();

    // ---- proj: wave pair covers (64 pix) x (18 of 36 cols); xpw uniform ----
    {
        const int wv = t >> 6, lane = t & 63;
        const int pg2 = __builtin_amdgcn_readfirstlane(wv & 1);
        const int pix = (wv >> 1) * 64 + lane;
        const int p0 = pg2 * 18;
        const int sw = pix & 7;
        float acc[18];
#pragma unroll
        for (int j = 0; j < 18; ++j) acc[j] = 0.f;
        for (int c4 = 0; c4 < 16; ++c4) {
            float xv0 = xt[pix * 64 + ((c4 * 4 + 0 + pix) & 63)];
            float xv1 = xt[pix * 64 + ((c4 * 4 + 1 + pix) & 63)];
            float xv2 = xt[pix * 64 + ((c4 * 4 + 2 + pix) & 63)];
            float xv3 = xt[pix * 64 + ((c4 * 4 + 3 + pix) & 63)];
#pragma unroll
            for (int j = 0; j < 18; ++j) {
                float4 wq = *(const float4*)&xpw[(p0 + j) * CC + c4 * 4];
                acc[j] = fmaf(wq.x, xv0, fmaf(wq.y, xv1,
                         fmaf(wq.z, xv2, fmaf(wq.w, xv3, acc[j]))));
            }
        }
        float* bp = &bcs[pix * 32];
        if (pg2 == 0) {
            *(float4*)&dtr[pix * 4] = make_float4(acc[0], acc[1], acc[2], acc[3]);
            // B groups 0..2 full; group 3 split (B12,B13 here)
            *(float4*)&bp[((0 ^ sw) << 2)] = make_float4(acc[4], acc[5], acc[6], acc[7]);
            *(float4*)&bp[((1 ^ sw) << 2)] = make_float4(acc[8], acc[9], acc[10], acc[11]);
            *(float4*)&bp[((2 ^ sw) << 2)] = make_float4(acc[12], acc[13], acc[14], acc[15]);
            bp[((3 ^ sw) << 2) + 0] = acc[16];
            bp[((3 ^ sw) << 2) + 1] = acc[17];
        } else {
            // B14,B15 finish group 3; C groups 4..7 full
            bp[((3 ^ sw) << 2) + 2] = acc[0];
            bp[((3 ^ sw) << 2) + 3] = acc[1];
            *(float4*)&bp[((4 ^ sw) << 2)] = make_float4(acc[2], acc[3], acc[4], acc[5]);
            *(float4*)&bp[((5 ^ sw) << 2)] = make_float4(acc[6], acc[7], acc[8], acc[9]);
            *(float4*)&bp[((6 ^ sw) << 2)] = make_float4(acc[10], acc[11], acc[12], acc[13]);
            *(float4*)&bp[((7 ^ sw) << 2)] = make_float4(acc[14], acc[15], acc[16], acc[17]);
        }
    }
    __syncthreads();                             // proj visible; LAST barrier

    // ---- scan setup; A pre-scaled by log2e so dA = v_exp directly ----
    const int d = t >> 2, ng = t & 3, n0 = ng * 4;
    const float L2E = 1.44269504088896340736f;
    float A0 = -__expf(A_log[d * NN + n0 + 0]) * L2E;
    float A1 = -__expf(A_log[d * NN + n0 + 1]) * L2E;
    float A2 = -__expf(A_log[d * NN + n0 + 2]) * L2E;
    float A3 = -__expf(A_log[d * NN + n0 + 3]) * L2E;
    const float Dd = Dv[d];
    float2 h01 = make_float2(0.f, 0.f), h23 = make_float2(0.f, 0.f);
    // delta inputs for THIS thread's d (values identical to old dlt path)
    const float4 wt4d = *(const float4*)&dtw[d * 4];
    const float bddd = dtb[d];
    float* drow = (half == 0 ? out : yv) + ((size_t)(b * CC + d) * 128 + L) * 128;

    // jj = ch*8+JL; jj&7 == JL (compile-time swizzle select).
#define SCAN_STEP(JL, DSRC)                                                    \
    {                                                                          \
        float delta = quad_bcast<(JL) & 3>(DSRC);                              \
        const int jj = ch * 8 + (JL);                                          \
        float u = xt[jj * 64 + ((d + jj) & 63)];                               \
        float4 Bv = *(const float4*)&bcs[jj * 32 + ((ng ^ (JL)) << 2)];        \
        float4 Cv = *(const float4*)&bcs[jj * 32 + (((4 + ng) ^ (JL)) << 2)];  \
        float du = delta * u;                                                  \
        float2 e01 = make_float2(EXP2F(delta * A0), EXP2F(delta * A1));        \
        float2 e23 = make_float2(EXP2F(delta * A2), EXP2F(delta * A3));        \
        float2 du2 = make_float2(du, du);                                      \
        h01 = f2fma(e01, h01, f2mul(du2, make_float2(Bv.x, Bv.y)));            \
        h23 = f2fma(e23, h23, f2mul(du2, make_float2(Bv.z, Bv.w)));            \
        float2 yt = f2fma(h23, make_float2(Cv.z, Cv.w),                        \
                          f2mul(h01, make_float2(Cv.x, Cv.y)));                \
        float y = yt.x + yt.y;                                                 \
        y += __shfl_xor(y, 1);                                                 \
        y += __shfl_xor(y, 2);                                                 \
        y = fmaf(u, Dd, y);                                                    \
        if (ng == ((JL) >> 1)) { if ((JL) & 1) y1 = y; else y0 = y; }          \
    }

#pragma unroll 1
    for (int ch = 0; ch < 16; ++ch) {
        // quad-parallel delta: lane ng owns steps jl=ng and jl=ng+4.
        // Same formula/fma order as old dlt phase -> bit-identical values.
        float4 drA = *(const float4*)&dtr[(ch * 8 + ng) * 4];
        float4 drB = *(const float4*)&dtr[(ch * 8 + 4 + ng) * 4];
        float da = softplus_f(fmaf(drA.x, wt4d.x, fmaf(drA.y, wt4d.y,
                   fmaf(drA.z, wt4d.z, fmaf(drA.w, wt4d.w, bddd)))));
        float db = softplus_f(fmaf(drB.x, wt4d.x, fmaf(drB.y, wt4d.y,
                   fmaf(drB.z, wt4d.z, fmaf(drB.w, wt4d.w, bddd)))));
        float y0 = 0.f, y1 = 0.f;
        SCAN_STEP(0, da) SCAN_STEP(1, da) SCAN_STEP(2, da) SCAN_STEP(3, da)
        SCAN_STEP(4, db) SCAN_STEP(5, db) SCAN_STEP(6, db) SCAN_STEP(7, db)
        *(float2*)&drow[ch * 8 + ng * 2] = make_float2(y0, y1);
        // fence: stop cross-chunk ds_read pipelining (R16-proven keeps 80 VGPR)
        __builtin_amdgcn_sched_barrier(0);
    }
#undef SCAN_STEP
}

// ===========================================================================
// out[b,c,h,w] += yv[b,c,w,h]  (32x32 LDS-tile transposed RMW). R11-proven.
// ===========================================================================
__global__ __launch_bounds__(256) void k_add(const float* __restrict__ yv,
                                             float* __restrict__ out)
{
    __shared__ float td[32 * 33];
    int t = threadIdx.x;
    int bc_ = blockIdx.x >> 4;
    int tb = blockIdx.x & 15;
    int w0 = (tb & 3) * 32;
    int h0 = (tb >> 2) * 32;
    const float* src = yv + (size_t)bc_ * HW;   // [w][h]
    float* dst = out + (size_t)bc_ * HW;        // [h][w]
    int r = t >> 3, q = t & 7;
    float4 v = *(const float4*)&src[(w0 + r) * HH + h0 + q * 4];
    td[r * 33 + q * 4 + 0] = v.x;
    td[r * 33 + q * 4 + 1] = v.y;
    td[r * 33 + q * 4 + 2] = v.z;
    td[r * 33 + q * 4 + 3] = v.w;
    __syncthreads();
    float* op = &dst[(h0 + r) * WW + w0 + q * 4];
    float4 o = *(float4*)op;
    o.x += td[(q * 4 + 0) * 33 + r];
    o.y += td[(q * 4 + 1) * 33 + r];
    o.z += td[(q * 4 + 2) * 33 + r];
    o.w += td[(q * 4 + 3) * 33 + r];
    *(float4*)op = o;
}

// ---------------------------------------------------------------------------
extern "C" void kernel_launch(void* const* d_in, const int* in_sizes, int n_in,
                              void* d_out, int out_size, void* d_ws, size_t ws_size,
                              hipStream_t stream) {
    const float* x     = (const float*)d_in[0];
    const float* A_log = (const float*)d_in[1];
    const float* Dv    = (const float*)d_in[2];
    const float* xpw   = (const float*)d_in[3];
    const float* dtw   = (const float*)d_in[4];
    const float* dtb   = (const float*)d_in[5];
    float* out = (float*)d_out;
    float* yv  = (float*)d_ws;       // 16.8 MB; ws >= 43 MB proven in R11

    k_scan<<<1024, 256, 0, stream>>>(x, xpw, A_log, Dv, dtw, dtb, out, yv);
    k_add <<<BB * CC * 16, 256, 0, stream>>>(yv, out);
}

// Round 11
// 142.007 us; speedup vs baseline: 2.3471x; 1.0140x over previous
//
#include <hip/hip_runtime.h>

#define BB 4
#define CC 64
#define HH 128
#define WW 128
#define NN 16
#define HW (HH*WW)

#if __has_builtin(__builtin_amdgcn_exp2f)
#define EXP2F(x) __builtin_amdgcn_exp2f(x)
#else
#define EXP2F(x) exp2f(x)
#endif

__device__ __forceinline__ float softplus_f(float x) {
    float e = __expf(-fabsf(x));
    return fmaxf(x, 0.0f) + __logf(1.0f + e);
}

// float2 helpers: written so SLP can form v_pk_fma_f32 / v_pk_mul_f32.
__device__ __forceinline__ float2 f2mul(float2 a, float2 b) {
    return make_float2(a.x * b.x, a.y * b.y);
}
__device__ __forceinline__ float2 f2fma(float2 a, float2 b, float2 c) {
    return make_float2(fmaf(a.x, b.x, c.x), fmaf(a.y, b.y, c.y));
}

// Broadcast quad lane (base+SRC) to all 4 quad lanes. Pure-VALU DPP quad_perm.
template<int SRC>
__device__ __forceinline__ float quad_bcast(float v) {
    return __int_as_float(__builtin_amdgcn_mov_dpp(
        __float_as_int(v), SRC * 0x55, 0xF, 0xF, true));
}
// Quad lane-swap xor 1 / xor 2 — pure-VALU replacement for __shfl_xor(y,1/2)
// (which can lower to ds_swizzle = DS-pipe issue). Bit-identical values.
__device__ __forceinline__ float quad_x1(float v) {   // quad_perm [1,0,3,2]
    return __int_as_float(__builtin_amdgcn_mov_dpp(
        __float_as_int(v), 0xB1, 0xF, 0xF, true));
}
__device__ __forceinline__ float quad_x2(float v) {   // quad_perm [2,3,0,1]
    return __int_as_float(__builtin_amdgcn_mov_dpp(
        __float_as_int(v), 0x4E, 0xF, 0xF, true));
}

// ===========================================================================
// Fused proj+scan. grid 1024, block 256 = 64 d x 4 ng (4 SSM states/lane).
// Blocks [0,512): h-scan of row (b,L=h) -> out[b,c,h,:]
// Blocks [512,1024): v-scan of col (b,L=w) -> yv[b,c,w,:]  ([b][c][w][h])
// R21 (resubmit — R10's bench was an infra failure, kernel never ran)
// = R20 (144.0us total, 71.9us k_scan, 76 VGPR — best known) minus two
// more DS-pipe consumers, same skeleton:
//  1. quad reduction shfl_xor(1/2) -> explicit DPP quad_perm adds (if hipcc
//     lowered shfl to ds_swizzle, that was 2 DS issues/step = biggest left)
//  2. u-reads 8/chunk -> 2/chunk: lane ng reads u for jl=ng,ng+4, quad-DPP
//     broadcast per step (the exact pattern R20 validated for delta).
// Model (R16/R18/R20 gradient): DS-pipe issue count and VALU co-dominate;
// ~160 DS issues removed ≈ 7.5us. All math bit-identical (same locations,
// same fma order). R19 lesson: ~62us of total is fixed harness overhead.
// ===========================================================================
__global__ __launch_bounds__(256) void k_scan(
    const float* __restrict__ x, const float* __restrict__ xpw,
    const float* __restrict__ A_log, const float* __restrict__ Dv,
    const float* __restrict__ dtw, const float* __restrict__ dtb,
    float* __restrict__ out, float* __restrict__ yv)
{
    __shared__ float xt[128 * 64];   // 32 KB  x line, (j,c) at j*64+((c+j)&63)
    __shared__ float bcs[128 * 32];  // 16 KB  B/C, group g at j*32+((g^(j&7))<<2)
    __shared__ float dtr[128 * 4];   //  2 KB  dt_raw per pixel

    const int t = threadIdx.x;
    const int half = blockIdx.x >> 9;          // R0-proven balanced mapping
    const int r9 = blockIdx.x & 511;
    const int b = r9 >> 7;
    const int L = r9 & 127;

    // ---- stage x line into swizzled xt ----
    if (half == 0) {
#pragma unroll
        for (int k = 0; k < 8; ++k) {            // rows: float4 coalesced global
            int i = k * 256 + t;
            int c = i >> 5, jq = i & 31;
            float4 v = *(const float4*)&x[((size_t)(b * CC + c) * HH + L) * WW + jq * 4];
            int j0 = jq * 4;
            xt[(j0 + 0) * 64 + ((c + j0 + 0) & 63)] = v.x;
            xt[(j0 + 1) * 64 + ((c + j0 + 1) & 63)] = v.y;
            xt[(j0 + 2) * 64 + ((c + j0 + 2) & 63)] = v.z;
            xt[(j0 + 3) * 64 + ((c + j0 + 3) & 63)] = v.w;
        }
    } else {
#pragma unroll
        for (int p = 0; p < 32; ++p) {           // cols: L2/L3-served gather
            int c = t & 63, j = p * 4 + (t >> 6);
            xt[j * 64 + ((c + j) & 63)] =
                x[((size_t)(b * CC + c) * HH + j) * WW + L];
        }
    }
    __syncthreads();

    // ---- proj: wave pair covers (64 pix) x (18 of 36 cols); xpw uniform ----
    {
        const int wv = t >> 6, lane = t & 63;
        const int pg2 = __builtin_amdgcn_readfirstlane(wv & 1);
        const int pix = (wv >> 1) * 64 + lane;
        const int p0 = pg2 * 18;
        const int sw = pix & 7;
        float acc[18];
#pragma unroll
        for (int j = 0; j < 18; ++j) acc[j] = 0.f;
        for (int c4 = 0; c4 < 16; ++c4) {
            float xv0 = xt[pix * 64 + ((c4 * 4 + 0 + pix) & 63)];
            float xv1 = xt[pix * 64 + ((c4 * 4 + 1 + pix) & 63)];
            float xv2 = xt[pix * 64 + ((c4 * 4 + 2 + pix) & 63)];
            float xv3 = xt[pix * 64 + ((c4 * 4 + 3 + pix) & 63)];
#pragma unroll
            for (int j = 0; j < 18; ++j) {
                float4 wq = *(const float4*)&xpw[(p0 + j) * CC + c4 * 4];
                acc[j] = fmaf(wq.x, xv0, fmaf(wq.y, xv1,
                         fmaf(wq.z, xv2, fmaf(wq.w, xv3, acc[j]))));
            }
        }
        float* bp = &bcs[pix * 32];
        if (pg2 == 0) {
            *(float4*)&dtr[pix * 4] = make_float4(acc[0], acc[1], acc[2], acc[3]);
            // B groups 0..2 full; group 3 split (B12,B13 here)
            *(float4*)&bp[((0 ^ sw) << 2)] = make_float4(acc[4], acc[5], acc[6], acc[7]);
            *(float4*)&bp[((1 ^ sw) << 2)] = make_float4(acc[8], acc[9], acc[10], acc[11]);
            *(float4*)&bp[((2 ^ sw) << 2)] = make_float4(acc[12], acc[13], acc[14], acc[15]);
            bp[((3 ^ sw) << 2) + 0] = acc[16];
            bp[((3 ^ sw) << 2) + 1] = acc[17];
        } else {
            // B14,B15 finish group 3; C groups 4..7 full
            bp[((3 ^ sw) << 2) + 2] = acc[0];
            bp[((3 ^ sw) << 2) + 3] = acc[1];
            *(float4*)&bp[((4 ^ sw) << 2)] = make_float4(acc[2], acc[3], acc[4], acc[5]);
            *(float4*)&bp[((5 ^ sw) << 2)] = make_float4(acc[6], acc[7], acc[8], acc[9]);
            *(float4*)&bp[((6 ^ sw) << 2)] = make_float4(acc[10], acc[11], acc[12], acc[13]);
            *(float4*)&bp[((7 ^ sw) << 2)] = make_float4(acc[14], acc[15], acc[16], acc[17]);
        }
    }
    __syncthreads();                             // proj visible; LAST barrier

    // ---- scan setup; A pre-scaled by log2e so dA = v_exp directly ----
    const int d = t >> 2, ng = t & 3, n0 = ng * 4;
    const float L2E = 1.44269504088896340736f;
    float A0 = -__expf(A_log[d * NN + n0 + 0]) * L2E;
    float A1 = -__expf(A_log[d * NN + n0 + 1]) * L2E;
    float A2 = -__expf(A_log[d * NN + n0 + 2]) * L2E;
    float A3 = -__expf(A_log[d * NN + n0 + 3]) * L2E;
    const float Dd = Dv[d];
    float2 h01 = make_float2(0.f, 0.f), h23 = make_float2(0.f, 0.f);
    // delta inputs for THIS thread's d (values identical to old dlt path)
    const float4 wt4d = *(const float4*)&dtw[d * 4];
    const float bddd = dtb[d];
    float* drow = (half == 0 ? out : yv) + ((size_t)(b * CC + d) * 128 + L) * 128;

    // jj = ch*8+JL; jj&7 == JL (compile-time swizzle select).
#define SCAN_STEP(JL, DSRC, USRC)                                              \
    {                                                                          \
        float delta = quad_bcast<(JL) & 3>(DSRC);                              \
        float u     = quad_bcast<(JL) & 3>(USRC);                              \
        const int jj = ch * 8 + (JL);                                          \
        float4 Bv = *(const float4*)&bcs[jj * 32 + ((ng ^ (JL)) << 2)];        \
        float4 Cv = *(const float4*)&bcs[jj * 32 + (((4 + ng) ^ (JL)) << 2)];  \
        float du = delta * u;                                                  \
        float2 e01 = make_float2(EXP2F(delta * A0), EXP2F(delta * A1));        \
        float2 e23 = make_float2(EXP2F(delta * A2), EXP2F(delta * A3));        \
        float2 du2 = make_float2(du, du);                                      \
        h01 = f2fma(e01, h01, f2mul(du2, make_float2(Bv.x, Bv.y)));            \
        h23 = f2fma(e23, h23, f2mul(du2, make_float2(Bv.z, Bv.w)));            \
        float2 yt = f2fma(h23, make_float2(Cv.z, Cv.w),                        \
                          f2mul(h01, make_float2(Cv.x, Cv.y)));                \
        float y = yt.x + yt.y;                                                 \
        y += quad_x1(y);                                                       \
        y += quad_x2(y);                                                       \
        y = fmaf(u, Dd, y);                                                    \
        if (ng == ((JL) >> 1)) { if ((JL) & 1) y1 = y; else y0 = y; }          \
    }

#pragma unroll 1
    for (int ch = 0; ch < 16; ++ch) {
        // quad-parallel delta+u: lane ng owns steps jl=ng and jl=ng+4.
        // Same formula/fma order/locations as before -> bit-identical.
        const int jA = ch * 8 + ng, jB = ch * 8 + 4 + ng;
        float4 drA = *(const float4*)&dtr[jA * 4];
        float4 drB = *(const float4*)&dtr[jB * 4];
        float uA = xt[jA * 64 + ((d + jA) & 63)];
        float uB = xt[jB * 64 + ((d + jB) & 63)];
        float da = softplus_f(fmaf(drA.x, wt4d.x, fmaf(drA.y, wt4d.y,
                   fmaf(drA.z, wt4d.z, fmaf(drA.w, wt4d.w, bddd)))));
        float db = softplus_f(fmaf(drB.x, wt4d.x, fmaf(drB.y, wt4d.y,
                   fmaf(drB.z, wt4d.z, fmaf(drB.w, wt4d.w, bddd)))));
        float y0 = 0.f, y1 = 0.f;
        SCAN_STEP(0, da, uA) SCAN_STEP(1, da, uA)
        SCAN_STEP(2, da, uA) SCAN_STEP(3, da, uA)
        SCAN_STEP(4, db, uB) SCAN_STEP(5, db, uB)
        SCAN_STEP(6, db, uB) SCAN_STEP(7, db, uB)
        *(float2*)&drow[ch * 8 + ng * 2] = make_float2(y0, y1);
        // fence: stop cross-chunk ds_read pipelining (R16/R20-proven 76 VGPR)
        __builtin_amdgcn_sched_barrier(0);
    }
#undef SCAN_STEP
}

// ===========================================================================
// out[b,c,h,w] += yv[b,c,w,h]  (32x32 LDS-tile transposed RMW). R11-proven.
// ===========================================================================
__global__ __launch_bounds__(256) void k_add(const float* __restrict__ yv,
                                             float* __restrict__ out)
{
    __shared__ float td[32 * 33];
    int t = threadIdx.x;
    int bc_ = blockIdx.x >> 4;
    int tb = blockIdx.x & 15;
    int w0 = (tb & 3) * 32;
    int h0 = (tb >> 2) * 32;
    const float* src = yv + (size_t)bc_ * HW;   // [w][h]
    float* dst = out + (size_t)bc_ * HW;        // [h][w]
    int r = t >> 3, q = t & 7;
    float4 v = *(const float4*)&src[(w0 + r) * HH + h0 + q * 4];
    td[r * 33 + q * 4 + 0] = v.x;
    td[r * 33 + q * 4 + 1] = v.y;
    td[r * 33 + q * 4 + 2] = v.z;
    td[r * 33 + q * 4 + 3] = v.w;
    __syncthreads();
    float* op = &dst[(h0 + r) * WW + w0 + q * 4];
    float4 o = *(float4*)op;
    o.x += td[(q * 4 + 0) * 33 + r];
    o.y += td[(q * 4 + 1) * 33 + r];
    o.z += td[(q * 4 + 2) * 33 + r];
    o.w += td[(q * 4 + 3) * 33 + r];
    *(float4*)op = o;
}

// ---------------------------------------------------------------------------
extern "C" void kernel_launch(void* const* d_in, const int* in_sizes, int n_in,
                              void* d_out, int out_size, void* d_ws, size_t ws_size,
                              hipStream_t stream) {
    const float* x     = (const float*)d_in[0];
    const float* A_log = (const float*)d_in[1];
    const float* Dv    = (const float*)d_in[2];
    const float* xpw   = (const float*)d_in[3];
    const float* dtw   = (const float*)d_in[4];
    const float* dtb   = (const float*)d_in[5];
    float* out = (float*)d_out;
    float* yv  = (float*)d_ws;       // 16.8 MB; ws >= 43 MB proven in R11

    k_scan<<<1024, 256, 0, stream>>>(x, xpw, A_log, Dv, dtw, dtb, out, yv);
    k_add <<<BB * CC * 16, 256, 0, stream>>>(yv, out);
}

// Round 12
// 138.881 us; speedup vs baseline: 2.3999x; 1.0225x over previous
//
#include <hip/hip_runtime.h>

#define BB 4
#define CC 64
#define HH 128
#define WW 128
#define NN 16
#define HW (HH*WW)

#if __has_builtin(__builtin_amdgcn_exp2f)
#define EXP2F(x) __builtin_amdgcn_exp2f(x)
#else
#define EXP2F(x) exp2f(x)
#endif

__device__ __forceinline__ float softplus_f(float x) {
    float e = __expf(-fabsf(x));
    return fmaxf(x, 0.0f) + __logf(1.0f + e);
}

// float2 helpers: written so SLP can form v_pk_fma_f32 / v_pk_mul_f32.
__device__ __forceinline__ float2 f2mul(float2 a, float2 b) {
    return make_float2(a.x * b.x, a.y * b.y);
}
__device__ __forceinline__ float2 f2fma(float2 a, float2 b, float2 c) {
    return make_float2(fmaf(a.x, b.x, c.x), fmaf(a.y, b.y, c.y));
}

// Broadcast quad lane (base+SRC) to all 4 quad lanes. Pure-VALU DPP quad_perm.
template<int SRC>
__device__ __forceinline__ float quad_bcast(float v) {
    return __int_as_float(__builtin_amdgcn_mov_dpp(
        __float_as_int(v), SRC * 0x55, 0xF, 0xF, true));
}
// Quad lane-swap xor 1 / xor 2 — pure-VALU quad reduction.
__device__ __forceinline__ float quad_x1(float v) {   // quad_perm [1,0,3,2]
    return __int_as_float(__builtin_amdgcn_mov_dpp(
        __float_as_int(v), 0xB1, 0xF, 0xF, true));
}
__device__ __forceinline__ float quad_x2(float v) {   // quad_perm [2,3,0,1]
    return __int_as_float(__builtin_amdgcn_mov_dpp(
        __float_as_int(v), 0x4E, 0xF, 0xF, true));
}

// ===========================================================================
// Fused proj+scan. grid 1024, block 256 = 64 d x 4 ng (4 SSM states/lane).
// Blocks [0,512): h-scan of row (b,L=h) -> out[b,c,h,:]
// Blocks [512,1024): v-scan of col (b,L=w) -> yv[b,c,w,:]  ([b][c][w][h])
// R22 = R21 (142.0us total, ~69us k_scan, 76 VGPR — best known) + two
// surgical scan-loop cuts, same skeleton:
//  1. chunk-top dtr/u loads software-pipelined: prefetch ch+1's drA/drB/
//     uA/uB inside ch's body (8-step body hides the LDS latency that
//     serialized each chunk start). Fence stays -> pressure contained.
//  2. delta*A via v_pk_mul (A01/A23 float2): 2 instead of 4 muls/step.
// Model (R16/R18/R20/R21): scan is VALU-issue+latency bound at ~61% busy;
// exp count (512/wave) is irreducible; remaining levers are latency hiding
// and issue trim. Math bit-identical -> absmax 0.125.
// R21 note: u-read 4-way bank conflict (1.2M counter) measured harmless.
// ===========================================================================
__global__ __launch_bounds__(256) void k_scan(
    const float* __restrict__ x, const float* __restrict__ xpw,
    const float* __restrict__ A_log, const float* __restrict__ Dv,
    const float* __restrict__ dtw, const float* __restrict__ dtb,
    float* __restrict__ out, float* __restrict__ yv)
{
    __shared__ float xt[128 * 64];   // 32 KB  x line, (j,c) at j*64+((c+j)&63)
    __shared__ float bcs[128 * 32];  // 16 KB  B/C, group g at j*32+((g^(j&7))<<2)
    __shared__ float dtr[128 * 4];   //  2 KB  dt_raw per pixel

    const int t = threadIdx.x;
    const int half = blockIdx.x >> 9;          // R0-proven balanced mapping
    const int r9 = blockIdx.x & 511;
    const int b = r9 >> 7;
    const int L = r9 & 127;

    // ---- stage x line into swizzled xt ----
    if (half == 0) {
#pragma unroll
        for (int k = 0; k < 8; ++k) {            // rows: float4 coalesced global
            int i = k * 256 + t;
            int c = i >> 5, jq = i & 31;
            float4 v = *(const float4*)&x[((size_t)(b * CC + c) * HH + L) * WW + jq * 4];
            int j0 = jq * 4;
            xt[(j0 + 0) * 64 + ((c + j0 + 0) & 63)] = v.x;
            xt[(j0 + 1) * 64 + ((c + j0 + 1) & 63)] = v.y;
            xt[(j0 + 2) * 64 + ((c + j0 + 2) & 63)] = v.z;
            xt[(j0 + 3) * 64 + ((c + j0 + 3) & 63)] = v.w;
        }
    } else {
#pragma unroll
        for (int p = 0; p < 32; ++p) {           // cols: L2/L3-served gather
            int c = t & 63, j = p * 4 + (t >> 6);
            xt[j * 64 + ((c + j) & 63)] =
                x[((size_t)(b * CC + c) * HH + j) * WW + L];
        }
    }
    __syncthreads();

    // ---- proj: wave pair covers (64 pix) x (18 of 36 cols); xpw uniform ----
    {
        const int wv = t >> 6, lane = t & 63;
        const int pg2 = __builtin_amdgcn_readfirstlane(wv & 1);
        const int pix = (wv >> 1) * 64 + lane;
        const int p0 = pg2 * 18;
        const int sw = pix & 7;
        float acc[18];
#pragma unroll
        for (int j = 0; j < 18; ++j) acc[j] = 0.f;
        for (int c4 = 0; c4 < 16; ++c4) {
            float xv0 = xt[pix * 64 + ((c4 * 4 + 0 + pix) & 63)];
            float xv1 = xt[pix * 64 + ((c4 * 4 + 1 + pix) & 63)];
            float xv2 = xt[pix * 64 + ((c4 * 4 + 2 + pix) & 63)];
            float xv3 = xt[pix * 64 + ((c4 * 4 + 3 + pix) & 63)];
#pragma unroll
            for (int j = 0; j < 18; ++j) {
                float4 wq = *(const float4*)&xpw[(p0 + j) * CC + c4 * 4];
                acc[j] = fmaf(wq.x, xv0, fmaf(wq.y, xv1,
                         fmaf(wq.z, xv2, fmaf(wq.w, xv3, acc[j]))));
            }
        }
        float* bp = &bcs[pix * 32];
        if (pg2 == 0) {
            *(float4*)&dtr[pix * 4] = make_float4(acc[0], acc[1], acc[2], acc[3]);
            // B groups 0..2 full; group 3 split (B12,B13 here)
            *(float4*)&bp[((0 ^ sw) << 2)] = make_float4(acc[4], acc[5], acc[6], acc[7]);
            *(float4*)&bp[((1 ^ sw) << 2)] = make_float4(acc[8], acc[9], acc[10], acc[11]);
            *(float4*)&bp[((2 ^ sw) << 2)] = make_float4(acc[12], acc[13], acc[14], acc[15]);
            bp[((3 ^ sw) << 2) + 0] = acc[16];
            bp[((3 ^ sw) << 2) + 1] = acc[17];
        } else {
            // B14,B15 finish group 3; C groups 4..7 full
            bp[((3 ^ sw) << 2) + 2] = acc[0];
            bp[((3 ^ sw) << 2) + 3] = acc[1];
            *(float4*)&bp[((4 ^ sw) << 2)] = make_float4(acc[2], acc[3], acc[4], acc[5]);
            *(float4*)&bp[((5 ^ sw) << 2)] = make_float4(acc[6], acc[7], acc[8], acc[9]);
            *(float4*)&bp[((6 ^ sw) << 2)] = make_float4(acc[10], acc[11], acc[12], acc[13]);
            *(float4*)&bp[((7 ^ sw) << 2)] = make_float4(acc[14], acc[15], acc[16], acc[17]);
        }
    }
    __syncthreads();                             // proj visible; LAST barrier

    // ---- scan setup; A pre-scaled by log2e so dA = v_exp directly ----
    const int d = t >> 2, ng = t & 3, n0 = ng * 4;
    const float L2E = 1.44269504088896340736f;
    const float2 A01 = make_float2(-__expf(A_log[d * NN + n0 + 0]) * L2E,
                                   -__expf(A_log[d * NN + n0 + 1]) * L2E);
    const float2 A23 = make_float2(-__expf(A_log[d * NN + n0 + 2]) * L2E,
                                   -__expf(A_log[d * NN + n0 + 3]) * L2E);
    const float Dd = Dv[d];
    float2 h01 = make_float2(0.f, 0.f), h23 = make_float2(0.f, 0.f);
    // delta inputs for THIS thread's d (values identical to old dlt path)
    const float4 wt4d = *(const float4*)&dtw[d * 4];
    const float bddd = dtb[d];
    float* drow = (half == 0 ? out : yv) + ((size_t)(b * CC + d) * 128 + L) * 128;

    // jj = ch*8+JL; jj&7 == JL (compile-time swizzle select).
#define SCAN_STEP(JL, DSRC, USRC)                                              \
    {                                                                          \
        float delta = quad_bcast<(JL) & 3>(DSRC);                              \
        float u     = quad_bcast<(JL) & 3>(USRC);                              \
        const int jj = ch * 8 + (JL);                                          \
        float4 Bv = *(const float4*)&bcs[jj * 32 + ((ng ^ (JL)) << 2)];        \
        float4 Cv = *(const float4*)&bcs[jj * 32 + (((4 + ng) ^ (JL)) << 2)];  \
        float du = delta * u;                                                  \
        float2 dd2 = make_float2(delta, delta);                                \
        float2 p01 = f2mul(dd2, A01);            /* v_pk_mul_f32 */            \
        float2 p23 = f2mul(dd2, A23);                                          \
        float2 e01 = make_float2(EXP2F(p01.x), EXP2F(p01.y));                  \
        float2 e23 = make_float2(EXP2F(p23.x), EXP2F(p23.y));                  \
        float2 du2 = make_float2(du, du);                                      \
        h01 = f2fma(e01, h01, f2mul(du2, make_float2(Bv.x, Bv.y)));            \
        h23 = f2fma(e23, h23, f2mul(du2, make_float2(Bv.z, Bv.w)));            \
        float2 yt = f2fma(h23, make_float2(Cv.z, Cv.w),                        \
                          f2mul(h01, make_float2(Cv.x, Cv.y)));                \
        float y = yt.x + yt.y;                                                 \
        y += quad_x1(y);                                                       \
        y += quad_x2(y);                                                       \
        y = fmaf(u, Dd, y);                                                    \
        if (ng == ((JL) >> 1)) { if ((JL) & 1) y1 = y; else y0 = y; }          \
    }

    // prefetch chunk 0's delta/u inputs
    float4 drA = *(const float4*)&dtr[ng * 4];
    float4 drB = *(const float4*)&dtr[(4 + ng) * 4];
    float uA = xt[ng * 64 + ((d + ng) & 63)];
    float uB = xt[(4 + ng) * 64 + ((d + 4 + ng) & 63)];

#pragma unroll 1
    for (int ch = 0; ch < 16; ++ch) {
        // current chunk's deltas (loads landed during previous chunk's body)
        float da = softplus_f(fmaf(drA.x, wt4d.x, fmaf(drA.y, wt4d.y,
                   fmaf(drA.z, wt4d.z, fmaf(drA.w, wt4d.w, bddd)))));
        float db = softplus_f(fmaf(drB.x, wt4d.x, fmaf(drB.y, wt4d.y,
                   fmaf(drB.z, wt4d.z, fmaf(drB.w, wt4d.w, bddd)))));
        // prefetch chunk ch+1 (clamped; redundant re-read on last chunk is
        // harmless and keeps the loop branch-free). Scheduler is free to
        // hoist these above the steps — results only used next iteration.
        const int chn = ch < 15 ? ch + 1 : 15;
        const int jA = chn * 8 + ng, jB = chn * 8 + 4 + ng;
        float4 n_drA = *(const float4*)&dtr[jA * 4];
        float4 n_drB = *(const float4*)&dtr[jB * 4];
        float n_uA = xt[jA * 64 + ((d + jA) & 63)];
        float n_uB = xt[jB * 64 + ((d + jB) & 63)];

        float y0 = 0.f, y1 = 0.f;
        SCAN_STEP(0, da, uA) SCAN_STEP(1, da, uA)
        SCAN_STEP(2, da, uA) SCAN_STEP(3, da, uA)
        SCAN_STEP(4, db, uB) SCAN_STEP(5, db, uB)
        SCAN_STEP(6, db, uB) SCAN_STEP(7, db, uB)
        *(float2*)&drow[ch * 8 + ng * 2] = make_float2(y0, y1);

        drA = n_drA; drB = n_drB; uA = n_uA; uB = n_uB;
        // fence: stop cross-chunk ds_read pipelining beyond the explicit
        // prefetch (R16/R20/R21-proven keeps VGPR ~76-96)
        __builtin_amdgcn_sched_barrier(0);
    }
#undef SCAN_STEP
}

// ===========================================================================
// out[b,c,h,w] += yv[b,c,w,h]  (32x32 LDS-tile transposed RMW). R11-proven.
// ===========================================================================
__global__ __launch_bounds__(256) void k_add(const float* __restrict__ yv,
                                             float* __restrict__ out)
{
    __shared__ float td[32 * 33];
    int t = threadIdx.x;
    int bc_ = blockIdx.x >> 4;
    int tb = blockIdx.x & 15;
    int w0 = (tb & 3) * 32;
    int h0 = (tb >> 2) * 32;
    const float* src = yv + (size_t)bc_ * HW;   // [w][h]
    float* dst = out + (size_t)bc_ * HW;        // [h][w]
    int r = t >> 3, q = t & 7;
    float4 v = *(const float4*)&src[(w0 + r) * HH + h0 + q * 4];
    td[r * 33 + q * 4 + 0] = v.x;
    td[r * 33 + q * 4 + 1] = v.y;
    td[r * 33 + q * 4 + 2] = v.z;
    td[r * 33 + q * 4 + 3] = v.w;
    __syncthreads();
    float* op = &dst[(h0 + r) * WW + w0 + q * 4];
    float4 o = *(float4*)op;
    o.x += td[(q * 4 + 0) * 33 + r];
    o.y += td[(q * 4 + 1) * 33 + r];
    o.z += td[(q * 4 + 2) * 33 + r];
    o.w += td[(q * 4 + 3) * 33 + r];
    *(float4*)op = o;
}

// ---------------------------------------------------------------------------
extern "C" void kernel_launch(void* const* d_in, const int* in_sizes, int n_in,
                              void* d_out, int out_size, void* d_ws, size_t ws_size,
                              hipStream_t stream) {
    const float* x     = (const float*)d_in[0];
    const float* A_log = (const float*)d_in[1];
    const float* Dv    = (const float*)d_in[2];
    const float* xpw   = (const float*)d_in[3];
    const float* dtw   = (const float*)d_in[4];
    const float* dtb   = (const float*)d_in[5];
    float* out = (float*)d_out;
    float* yv  = (float*)d_ws;       // 16.8 MB; ws >= 43 MB proven in R11

    k_scan<<<1024, 256, 0, stream>>>(x, xpw, A_log, Dv, dtw, dtb, out, yv);
    k_add <<<BB * CC * 16, 256, 0, stream>>>(yv, out);
}